// Round 6
// baseline (280.493 us; speedup 1.0000x reference)
//
#include <hip/hip_runtime.h>

// BaseEncoder: x[B,F] fp32 -> out[B,F,32] fp32
//   out[...,0]   = (x < 0) ? 1 : 0
//   out[...,1+d] = bit (30-d) of bitcast(x)   (bits 30..0; abs() only clears
//                  bit 31, so bits 30..0 of x equal bits 30..0 of |x|)
//
// R8c: third submission of the R8 experiment. Rounds 4 and 5 both died on
// container acquisition ("MI355X container failed twice") with no compile
// or correctness diagnostic. Source hash changed (comments + kernel symbol
// renamed) in case the failure is keyed on the previous source hash; the
// machine code and the experiment are unchanged.
//
// Experiment: moving-front + PLAIN stores (the untested cell).
//   - Load-side structure proven irrelevant (R4/R5/R6 all ~equal).
//   - NT->plain stores: only -7us (R7 = 262.6us).
//   - Kernel-side still ~2.9 TB/s vs the rocclr fill's 6.4 TB/s.
// Hypothesis: R7's 2048 concurrent per-block write streams thrash DRAM row
// buffers; the fill's single grid-wide moving front concentrates writes in
// a narrow window (near-zero row misses). R4 had the front layout but was
// poisoned by NT + per-store predicates. This kernel:
//   quad(k) = tid + k*STRIDE      (one contiguous 4 MiB front per step)
//   element = (tid>>3) + k*STRIDE/8,  channel phase = tid&7 (invariant)
//   16,777,216 quads = 1024 blocks * 256 thr * 64 steps EXACT -> no guards
//   GRID=1024 (4 blocks/CU): fewer concurrent streams, tighter front.
//   Batch-8: 8 independent broadcast loads, then 8 unbroken dwordx4 stores.

typedef float f32x4 __attribute__((ext_vector_type(4)));

constexpr int BLOCK = 256;
constexpr int GRID = 1024;
constexpr int STRIDE = GRID * BLOCK;       // 262144 quads = 4 MiB front/step
constexpr int STEPS = 64;                  // n_quads / STRIDE exactly
constexpr int BATCH = 8;

__global__ __launch_bounds__(BLOCK) void be_front_r8c(
    const float* __restrict__ x, f32x4* __restrict__ out) {
  const int tid = blockIdx.x * BLOCK + threadIdx.x;
  const int e0 = tid >> 3;                 // element slot (8 lanes/element)
  const int j0 = (tid & 7) << 2;           // channel phase, thread-invariant
  const bool sign_lane = (j0 == 0);
  const int s0 = 31 - j0, s1 = 30 - j0, s2 = 29 - j0, s3 = 28 - j0;

#pragma unroll
  for (int kb = 0; kb < STEPS; kb += BATCH) {
    float xv[BATCH];
#pragma unroll
    for (int i = 0; i < BATCH; ++i)
      xv[i] = x[e0 + (kb + i) * (STRIDE / 8)];
#pragma unroll
    for (int i = 0; i < BATCH; ++i) {
      const unsigned r = __float_as_uint(xv[i]);
      f32x4 o;
      // channel 0 is the exact sign channel (x<0), not the sign bit:
      // keeps -0.0 / NaN semantics identical to the reference.
      o.x = sign_lane ? ((xv[i] < 0.0f) ? 1.0f : 0.0f)
                      : (float)((r >> s0) & 1u);
      o.y = (float)((r >> s1) & 1u);
      o.z = (float)((r >> s2) & 1u);
      o.w = (float)((r >> s3) & 1u);
      out[tid + (kb + i) * STRIDE] = o;
    }
  }
}

// Fallback for shapes that don't divide exactly (plain stores).
__global__ __launch_bounds__(BLOCK) void be_gs_r8c(
    const float* __restrict__ x, f32x4* __restrict__ out, int n_quads) {
  const int stride = GRID * BLOCK;
  int tid = blockIdx.x * BLOCK + threadIdx.x;
  const int j0 = (tid & 7) << 2;
  const bool sign_lane = (j0 == 0);

  for (int base = tid; base < n_quads; base += 4 * stride) {
    int idx[4];
    float xv[4];
#pragma unroll
    for (int k = 0; k < 4; ++k) {
      idx[k] = base + k * stride;
      xv[k] = (idx[k] < n_quads) ? x[idx[k] >> 3] : 0.0f;
    }
#pragma unroll
    for (int k = 0; k < 4; ++k) {
      if (idx[k] < n_quads) {
        unsigned r = __float_as_uint(xv[k]);
        f32x4 o;
        o.x = (float)((r >> (31 - j0)) & 1u);
        o.y = (float)((r >> (30 - j0)) & 1u);
        o.z = (float)((r >> (29 - j0)) & 1u);
        o.w = (float)((r >> (28 - j0)) & 1u);
        if (sign_lane) o.x = (xv[k] < 0.0f) ? 1.0f : 0.0f;
        out[idx[k]] = o;
      }
    }
  }
}

extern "C" void kernel_launch(void* const* d_in, const int* in_sizes, int n_in,
                              void* d_out, int out_size, void* d_ws, size_t ws_size,
                              hipStream_t stream) {
  const float* x = (const float*)d_in[0];
  f32x4* out = (f32x4*)d_out;
  int n_elems = in_sizes[0];               // 4096*512 = 2,097,152
  int n_quads = n_elems * 8;               // 16,777,216 = GRID*BLOCK*STEPS
  if (n_quads == STRIDE * STEPS) {
    be_front_r8c<<<GRID, BLOCK, 0, stream>>>(x, out);
  } else {
    be_gs_r8c<<<GRID, BLOCK, 0, stream>>>(x, out, n_quads);
  }
}